// Round 9
// baseline (209.480 us; speedup 1.0000x reference)
//
#include <hip/hip_runtime.h>
#include <hip/hip_cooperative_groups.h>
#include <math.h>

namespace cg = cooperative_groups;

// GeneralLPModel: 2 x { row-normalize -> scatter-add(edges) -> relu(agg @ W) } -> softmax
// R9: whole pipeline in ONE cooperative kernel (grid.sync between phases).
//   Branch-and-bound gates (R8) become in-kernel phase skips: dead path =
//   prep0 + 2 grid syncs + final. Fallback to the R8 multi-kernel path if
//   cooperative launch is rejected.

constexpr int N_NODES = 100000;
constexpr int N_EDGES = 2000000;
constexpr int C       = 40;
constexpr int CV      = C / 4;        // 10 float4 chunks per row
constexpr int NB      = 782;          // coarse buckets: dst>>7
constexpr int BCAP    = 3072;         // per-bucket capacity (mean 2560, +10 sigma)
constexpr int BE      = 4096;         // edges per binpass block
constexpr int NBLK_BIN = (N_EDGES + BE - 1) / BE;   // 489
constexpr int NODE_BLK = (N_NODES + 255) / 256;     // 391
constexpr int NT      = 16;           // src tiles (src>>13)
constexpr int GRID_CO = 512;          // cooperative grid (2 blocks/CU -- deadlock-safe)

// ======================= device phase helpers ================================

// one edge-chunk of the coarse binning pass (needs hist[NB], base[NB] shared)
__device__ __forceinline__ void binpass_chunk(const int* __restrict__ ei,
                                              int* __restrict__ gcur,
                                              int* __restrict__ bucketed,
                                              int* hist, int* base, int chunk) {
    int tid = threadIdx.x;
    for (int b = tid; b < NB; b += 256) hist[b] = 0;
    __syncthreads();

    int e0 = chunk * BE;
    int e1 = min(e0 + BE, N_EDGES);
    for (int e = e0 + tid; e < e1; e += 256)
        atomicAdd(&hist[ei[N_EDGES + e] >> 7], 1);
    __syncthreads();

    for (int b = tid; b < NB; b += 256) {
        int c = hist[b];
        base[b] = c ? atomicAdd(&gcur[b], c) : 0;
        hist[b] = 0;                      // reuse as local cursor
    }
    __syncthreads();

    for (int e = e0 + tid; e < e1; e += 256) {
        int s = ei[e];
        int d = ei[N_EDGES + e];
        int b = d >> 7;
        int lp = atomicAdd(&hist[b], 1);
        int pos = base[b] + lp;
        if (pos < BCAP) bucketed[b * BCAP + pos] = (s << 7) | (d & 127);
    }
    __syncthreads();                      // safe reuse across loop iterations
}

// exclusive scan of the NB bucket counts, single block of 256 threads
__device__ __forceinline__ void scan782(const int* __restrict__ gcur,
                                        int* __restrict__ bbase,
                                        int (*pb)[256]) {
    int tid = threadIdx.x;
    int v[4];
    int sum = 0;
#pragma unroll
    for (int k = 0; k < 4; ++k) {
        int idx = tid * 4 + k;
        v[k] = (idx < NB) ? gcur[idx] : 0;
        sum += v[k];
    }
    pb[0][tid] = sum;
    __syncthreads();
    int p = 0;
    for (int d = 1; d < 256; d <<= 1) {
        int t = pb[p][tid];
        if (tid >= d) t += pb[p][tid - d];
        pb[p ^ 1][tid] = t;
        __syncthreads();
        p ^= 1;
    }
    int excl = pb[p][tid] - sum;
#pragma unroll
    for (int k = 0; k < 4; ++k) {
        int idx = tid * 4 + k;
        if (idx < NB) bbase[idx] = excl;
        excl += v[k];
    }
    __syncthreads();
}

// one bucket of the local counting sort (needs cnt/loff[128*NT], pbuf shared)
__device__ __forceinline__ void localsort_bucket(const int* __restrict__ gcur,
                                                 const int* __restrict__ bbase,
                                                 const int* __restrict__ bucketed,
                                                 int* __restrict__ offsets,
                                                 int* __restrict__ sorted_src,
                                                 int* cnt, int* loff,
                                                 int (*pb)[256], int b) {
    int c = min(gcur[b], BCAP);
    int base = bbase[b];
    int tid = threadIdx.x;

    for (int k = tid; k < 128 * NT; k += 256) cnt[k] = 0;
    __syncthreads();

    for (int j = tid; j < c; j += 256) {
        int v = bucketed[b * BCAP + j];
        int key = ((v & 127) << 4) | ((v >> 7) >> 13);
        atomicAdd(&cnt[key], 1);
    }
    __syncthreads();

    // 2-level exclusive scan over 2048 counters: 8 keys per thread
    int sum = 0;
#pragma unroll
    for (int k = 0; k < 8; ++k) sum += cnt[tid * 8 + k];
    pb[0][tid] = sum;
    __syncthreads();
    int p = 0;
    for (int d = 1; d < 256; d <<= 1) {
        int t = pb[p][tid];
        if (tid >= d) t += pb[p][tid - d];
        pb[p ^ 1][tid] = t;
        __syncthreads();
        p ^= 1;
    }
    int run = pb[p][tid] - sum;
#pragma unroll
    for (int k = 0; k < 8; ++k) { loff[tid * 8 + k] = run; run += cnt[tid * 8 + k]; }
    __syncthreads();

    int gd = b * 128 + tid;
    if (tid < 128 && gd < N_NODES) offsets[gd] = base + loff[tid << 4];
    if (b == NB - 1 && tid == 0) offsets[N_NODES] = N_EDGES;

    for (int k = tid; k < 128 * NT; k += 256) cnt[k] = 0;   // reuse as cursors
    __syncthreads();

    for (int j = tid; j < c; j += 256) {
        int v = bucketed[b * BCAP + j];
        int s = v >> 7;
        int key = ((v & 127) << 4) | (s >> 13);
        int lp = atomicAdd(&cnt[key], 1);
        sorted_src[base + loff[key] + lp] = s;
    }
    __syncthreads();                      // safe reuse across loop iterations
}

// per-node projection: y[i] = f(src[i]) @ Wl, f = (optional relu) + row-normalize
template <bool RELU_IN, bool NEED>
__device__ __forceinline__ void prep_node(const float* __restrict__ src,
                                          const float* Wl,
                                          float* __restrict__ y,
                                          int i, int* __restrict__ needflag) {
    float a[C];
    const float4* row = reinterpret_cast<const float4*>(src + (size_t)i * C);
    float ss = 0.f;
#pragma unroll
    for (int q = 0; q < CV; ++q) {
        float4 v = row[q];
        float p0 = RELU_IN ? fmaxf(v.x, 0.f) : v.x;
        float p1 = RELU_IN ? fmaxf(v.y, 0.f) : v.y;
        float p2 = RELU_IN ? fmaxf(v.z, 0.f) : v.z;
        float p3 = RELU_IN ? fmaxf(v.w, 0.f) : v.w;
        a[q * 4 + 0] = p0; a[q * 4 + 1] = p1; a[q * 4 + 2] = p2; a[q * 4 + 3] = p3;
        ss += p0 * p0 + p1 * p1 + p2 * p2 + p3 * p3;
    }
    float inv = 1.0f / (sqrtf(ss) + 1e-15f);
#pragma unroll
    for (int c = 0; c < C; ++c) a[c] *= inv;

    float o[C];
#pragma unroll
    for (int c = 0; c < C; ++c) o[c] = 0.f;
    for (int k = 0; k < C; ++k) {
        float ak = a[k];
#pragma unroll
        for (int c = 0; c < C; ++c) o[c] = fmaf(ak, Wl[k * C + c], o[c]);
    }

    if (NEED) {
        float mx = o[0];
#pragma unroll
        for (int c = 1; c < C; ++c) mx = fmaxf(mx, o[c]);
        unsigned long long m = __ballot(mx > 0.f);
        if (m != 0ull && (threadIdx.x & 63) == (__ffsll((long long)m) - 1))
            atomicOr(needflag, 1);
    }

    float4* orow = reinterpret_cast<float4*>(y + (size_t)i * C);
#pragma unroll
    for (int q = 0; q < CV; ++q) {
        float4 v = {o[q * 4 + 0], o[q * 4 + 1], o[q * 4 + 2], o[q * 4 + 3]};
        orow[q] = v;
    }
}

// one gather work-item (node i, float4 chunk q), 4-deep pipelined
__device__ __forceinline__ void gather_item(const float* __restrict__ y,
                                            const int* __restrict__ offsets,
                                            const int* __restrict__ sorted_src,
                                            float* __restrict__ agg,
                                            int* __restrict__ outflag, int t) {
    int i = t / CV;
    int q = t - i * CV;
    int beg = offsets[i], end = offsets[i + 1];
    const float* base = y + (size_t)q * 4;

    float4 a0 = {0.f,0.f,0.f,0.f}, a1 = {0.f,0.f,0.f,0.f};
    float4 a2 = {0.f,0.f,0.f,0.f}, a3 = {0.f,0.f,0.f,0.f};

    int j = beg;
    for (; j + 4 <= end; j += 4) {
        int s0 = sorted_src[j + 0];
        int s1 = sorted_src[j + 1];
        int s2 = sorted_src[j + 2];
        int s3 = sorted_src[j + 3];
        float4 v0 = *reinterpret_cast<const float4*>(base + (size_t)s0 * C);
        float4 v1 = *reinterpret_cast<const float4*>(base + (size_t)s1 * C);
        float4 v2 = *reinterpret_cast<const float4*>(base + (size_t)s2 * C);
        float4 v3 = *reinterpret_cast<const float4*>(base + (size_t)s3 * C);
        a0.x += v0.x; a0.y += v0.y; a0.z += v0.z; a0.w += v0.w;
        a1.x += v1.x; a1.y += v1.y; a1.z += v1.z; a1.w += v1.w;
        a2.x += v2.x; a2.y += v2.y; a2.z += v2.z; a2.w += v2.w;
        a3.x += v3.x; a3.y += v3.y; a3.z += v3.z; a3.w += v3.w;
    }
    for (; j < end; ++j) {
        int s = sorted_src[j];
        float4 v = *reinterpret_cast<const float4*>(base + (size_t)s * C);
        a0.x += v.x; a0.y += v.y; a0.z += v.z; a0.w += v.w;
    }

    float4 acc;
    acc.x = (a0.x + a1.x) + (a2.x + a3.x);
    acc.y = (a0.y + a1.y) + (a2.y + a3.y);
    acc.z = (a0.z + a1.z) + (a2.z + a3.z);
    acc.w = (a0.w + a1.w) + (a2.w + a3.w);
    *reinterpret_cast<float4*>(agg + (size_t)i * C + q * 4) = acc;

    if (outflag) {
        bool pos = (acc.x > 0.f) | (acc.y > 0.f) | (acc.z > 0.f) | (acc.w > 0.f);
        unsigned long long m = __ballot(pos);
        if (m != 0ull && (threadIdx.x & 63) == (__ffsll((long long)m) - 1))
            atomicOr(outflag, 1);
    }
}

// per-node epilogue: out[i] = softmax(relu(agg[i])) (zeros when !pos)
__device__ __forceinline__ void final_node(const float* __restrict__ agg,
                                           float* __restrict__ out,
                                           bool pos, int i) {
    float o[C];
    if (pos) {
        const float4* row = reinterpret_cast<const float4*>(agg + (size_t)i * C);
#pragma unroll
        for (int q = 0; q < CV; ++q) {
            float4 v = row[q];
            o[q * 4 + 0] = fmaxf(v.x, 0.f); o[q * 4 + 1] = fmaxf(v.y, 0.f);
            o[q * 4 + 2] = fmaxf(v.z, 0.f); o[q * 4 + 3] = fmaxf(v.w, 0.f);
        }
    } else {
#pragma unroll
        for (int c = 0; c < C; ++c) o[c] = 0.f;   // bit-identical to reading zeros
    }
    float m = o[0];
#pragma unroll
    for (int c = 1; c < C; ++c) m = fmaxf(m, o[c]);
    float s = 0.f;
#pragma unroll
    for (int c = 0; c < C; ++c) { o[c] = expf(o[c] - m); s += o[c]; }
    float inv = 1.0f / s;

    float4* orow = reinterpret_cast<float4*>(out + (size_t)i * C);
#pragma unroll
    for (int q = 0; q < CV; ++q) {
        float4 v = {o[q * 4 + 0] * inv, o[q * 4 + 1] * inv,
                    o[q * 4 + 2] * inv, o[q * 4 + 3] * inv};
        orow[q] = v;
    }
}

// ======================= fused cooperative kernel ============================
__global__ void fused_kernel(const float* x, const float* Ws, const int* ei,
                             float* y, int* gcur, int* bbase, int* posflag,
                             int* needflag, int* offsets, int* sorted_src,
                             int* bucketed, float* agg) {
    cg::grid_group grid = cg::this_grid();
    __shared__ float Wl[C * C];
    __shared__ int hist[NB], base[NB];
    __shared__ int cnt[128 * NT], loff[128 * NT];
    __shared__ int pbuf[2][256];

    const int gthreads = gridDim.x * blockDim.x;
    const int gtid = blockIdx.x * blockDim.x + threadIdx.x;

    // phase -1: zero cursors + flags
    for (int k = gtid; k < NB; k += gthreads) gcur[k] = 0;
    if (gtid == 0) { *posflag = 0; *needflag = 0; }
    grid.sync();

    // phase 0: prep0 (y0 = norm(x) @ W0, needflag = any(y0 > 0))
    for (int k = threadIdx.x; k < C * C; k += blockDim.x) Wl[k] = Ws[k];
    __syncthreads();
    for (int i = gtid; i < N_NODES; i += gthreads)
        prep_node<false, true>(x, Wl, y, i, needflag);
    grid.sync();

    bool need = (*(volatile int*)needflag) != 0;
    bool pos = false;
    if (need) {
        // CSR build
        for (int chunk = blockIdx.x; chunk < NBLK_BIN; chunk += gridDim.x)
            binpass_chunk(ei, gcur, bucketed, hist, base, chunk);
        grid.sync();
        if (blockIdx.x == 0) scan782(gcur, bbase, pbuf);
        grid.sync();
        for (int b = blockIdx.x; b < NB; b += gridDim.x)
            localsort_bucket(gcur, bbase, bucketed, offsets, sorted_src,
                             cnt, loff, pbuf, b);
        grid.sync();
        // iteration-0 aggregation
        for (int t = gtid; t < N_NODES * CV; t += gthreads)
            gather_item(y, offsets, sorted_src, agg, posflag, t);
        grid.sync();
        pos = (*(volatile int*)posflag) != 0;
        if (pos) {
            __syncthreads();
            for (int k = threadIdx.x; k < C * C; k += blockDim.x)
                Wl[k] = Ws[C * C + k];
            __syncthreads();
            for (int i = gtid; i < N_NODES; i += gthreads)
                prep_node<true, false>(agg, Wl, y, i, nullptr);
            grid.sync();
            for (int t = gtid; t < N_NODES * CV; t += gthreads)
                gather_item(y, offsets, sorted_src, agg, nullptr, t);
            grid.sync();
        }
    }

    // final: softmax(relu(agg)) or softmax(0)
    for (int i = gtid; i < N_NODES; i += gthreads)
        final_node(agg, y, pos, i);
}

// ======================= standalone fallback kernels (R8 path) ===============
__global__ void binpass_kernel(const int* __restrict__ ei, int* __restrict__ gcur,
                               int* __restrict__ bucketed, const int* __restrict__ gate) {
    if (*gate == 0) return;
    __shared__ int hist[NB], base[NB];
    binpass_chunk(ei, gcur, bucketed, hist, base, blockIdx.x);
}

__global__ void bucket_scan_kernel(const int* __restrict__ gcur,
                                   int* __restrict__ bbase,
                                   const int* __restrict__ gate) {
    if (*gate == 0) return;
    __shared__ int pbuf[2][256];
    scan782(gcur, bbase, pbuf);
}

__global__ void localsort_kernel(const int* __restrict__ gcur,
                                 const int* __restrict__ bbase,
                                 const int* __restrict__ bucketed,
                                 int* __restrict__ offsets,
                                 int* __restrict__ sorted_src,
                                 const int* __restrict__ gate) {
    if (*gate == 0) return;
    __shared__ int cnt[128 * NT], loff[128 * NT], pbuf[2][256];
    localsort_bucket(gcur, bbase, bucketed, offsets, sorted_src, cnt, loff,
                     pbuf, blockIdx.x);
}

__global__ void prep0_kernel(const float* __restrict__ x, const float* __restrict__ W,
                             float* __restrict__ y, int* __restrict__ needflag) {
    __shared__ float Wl[C * C];
    for (int k = threadIdx.x; k < C * C; k += blockDim.x) Wl[k] = W[k];
    __syncthreads();
    int i = blockIdx.x * blockDim.x + threadIdx.x;
    if (i >= N_NODES) return;
    prep_node<false, true>(x, Wl, y, i, needflag);
}

__global__ void prep1_kernel(const float* __restrict__ agg, const float* __restrict__ W,
                             float* __restrict__ y, const int* __restrict__ skipflag) {
    if (*skipflag == 0) return;
    __shared__ float Wl[C * C];
    for (int k = threadIdx.x; k < C * C; k += blockDim.x) Wl[k] = W[k];
    __syncthreads();
    int i = blockIdx.x * blockDim.x + threadIdx.x;
    if (i >= N_NODES) return;
    prep_node<true, false>(agg, Wl, y, i, nullptr);
}

__global__ void gather_kernel(const float* __restrict__ y, const int* __restrict__ offsets,
                              const int* __restrict__ sorted_src, float* __restrict__ agg,
                              const int* __restrict__ skipflag, int* __restrict__ outflag) {
    if (skipflag && *skipflag == 0) return;
    int t = blockIdx.x * blockDim.x + threadIdx.x;
    if (t >= N_NODES * CV) return;
    gather_item(y, offsets, sorted_src, agg, outflag, t);
}

__global__ void final_kernel(const float* __restrict__ agg, float* __restrict__ out,
                             const int* __restrict__ flag) {
    int i = blockIdx.x * blockDim.x + threadIdx.x;
    if (i >= N_NODES) return;
    final_node(agg, out, (*flag) != 0, i);
}

// ======================= launch ==============================================
extern "C" void kernel_launch(void* const* d_in, const int* in_sizes, int n_in,
                              void* d_out, int out_size, void* d_ws, size_t ws_size,
                              hipStream_t stream) {
    const float* x  = (const float*)d_in[0];
    const float* Ws = (const float*)d_in[1];   // [2, 40, 40]
    const int*   ei = (const int*)d_in[2];     // [2, 2M]

    float* y = (float*)d_out;                  // y table; final overwrites with out

    // workspace layout (ints), total ~24.4 MB
    int* wsI        = (int*)d_ws;
    int* gcur       = wsI;                     // [0, 1024)
    int* bbase      = wsI + 1024;              // [1024, 1806)
    int* posflag    = wsI + 2040;
    int* needflag   = wsI + 2041;
    int* offsets    = wsI + 2048;              // N_NODES+1 (reserve 102400)
    int* sorted_src = wsI + 104448;            // 2,000,000
    int* bucketed   = wsI + 2104448;           // NB*BCAP ints, aliases agg
    float* agg      = (float*)(wsI + 2104448); // 4,000,000 floats

    void* kargs[] = {
        (void*)&x, (void*)&Ws, (void*)&ei, (void*)&y,
        (void*)&gcur, (void*)&bbase, (void*)&posflag, (void*)&needflag,
        (void*)&offsets, (void*)&sorted_src, (void*)&bucketed, (void*)&agg,
    };
    hipError_t err = hipLaunchCooperativeKernel(
        (const void*)fused_kernel, dim3(GRID_CO), dim3(256), kargs, 0, stream);
    if (err == hipSuccess) return;

    // -------- fallback: proven R8 multi-kernel path --------
    (void)hipGetLastError();   // clear the error state
    const int BT = 256;
    const int nblk_gather = (N_NODES * CV + BT - 1) / BT;

    hipMemsetAsync(gcur, 0, NB * sizeof(int), stream);
    hipMemsetAsync(posflag, 0, 2 * sizeof(int), stream);

    prep0_kernel<<<NODE_BLK, BT, 0, stream>>>(x, Ws, y, needflag);
    binpass_kernel<<<NBLK_BIN, BT, 0, stream>>>(ei, gcur, bucketed, needflag);
    bucket_scan_kernel<<<1, 256, 0, stream>>>(gcur, bbase, needflag);
    localsort_kernel<<<NB, BT, 0, stream>>>(gcur, bbase, bucketed, offsets,
                                            sorted_src, needflag);
    gather_kernel<<<nblk_gather, BT, 0, stream>>>(y, offsets, sorted_src, agg,
                                                  needflag, posflag);
    prep1_kernel<<<NODE_BLK, BT, 0, stream>>>(agg, Ws + C * C, y, posflag);
    gather_kernel<<<nblk_gather, BT, 0, stream>>>(y, offsets, sorted_src, agg,
                                                  posflag, nullptr);
    final_kernel<<<NODE_BLK, BT, 0, stream>>>(agg, y, posflag);
}

// Round 10
// 42.114 us; speedup vs baseline: 4.9741x; 4.9741x over previous
//
#include <hip/hip_runtime.h>
#include <math.h>

// GeneralLPModel: 2 x { row-normalize -> scatter-add(edges) -> relu(agg @ W) } -> softmax
// R10: R8 multi-kernel structure (kernel-boundary acquire semantics make the
// flag gates safe -- R9's in-kernel volatile gate read stale cross-XCD L2).
// Changes vs R8: memsets -> 1-block init kernel; bucket_scan fused into
// localsort (redundant per-block LDS scan); gated grids capped + grid-stride
// to shrink empty-dispatch drain.

constexpr int N_NODES = 100000;
constexpr int N_EDGES = 2000000;
constexpr int C       = 40;
constexpr int CV      = C / 4;        // 10 float4 chunks per row
constexpr int NB      = 782;          // coarse buckets: dst>>7
constexpr int BCAP    = 3072;         // per-bucket capacity (mean 2560, +10 sigma)
constexpr int BE      = 4096;         // edges per binpass chunk
constexpr int NBLK_BIN = (N_EDGES + BE - 1) / BE;   // 489 chunks
constexpr int NODE_BLK = (N_NODES + 255) / 256;     // 391
constexpr int NT      = 16;           // src tiles (src>>13)

// ---- init: zero bucket cursors + flags (replaces 2 memsets) -----------------
__global__ void init_kernel(int* __restrict__ gcur, int* __restrict__ flags) {
    for (int k = threadIdx.x; k < NB; k += 256) gcur[k] = 0;
    if (threadIdx.x == 0) { flags[0] = 0; flags[1] = 0; }   // posflag, needflag
}

// ---- prep0: y0 = (x / (||x||+eps)) @ W0; needflag = any(y0 > 0) -------------
__global__ void prep0_kernel(const float* __restrict__ x,
                             const float* __restrict__ W,
                             float* __restrict__ y,
                             int* __restrict__ needflag) {
    __shared__ float Wl[C * C];
    for (int k = threadIdx.x; k < C * C; k += blockDim.x) Wl[k] = W[k];
    __syncthreads();

    int i = blockIdx.x * blockDim.x + threadIdx.x;
    if (i >= N_NODES) return;

    float a[C];
    const float4* row = reinterpret_cast<const float4*>(x + (size_t)i * C);
    float ss = 0.f;
#pragma unroll
    for (int q = 0; q < CV; ++q) {
        float4 v = row[q];
        a[q * 4 + 0] = v.x; a[q * 4 + 1] = v.y;
        a[q * 4 + 2] = v.z; a[q * 4 + 3] = v.w;
        ss += v.x * v.x + v.y * v.y + v.z * v.z + v.w * v.w;
    }
    float inv = 1.0f / (sqrtf(ss) + 1e-15f);
#pragma unroll
    for (int c = 0; c < C; ++c) a[c] *= inv;

    float o[C];
#pragma unroll
    for (int c = 0; c < C; ++c) o[c] = 0.f;
    for (int k = 0; k < C; ++k) {
        float ak = a[k];
#pragma unroll
        for (int c = 0; c < C; ++c) o[c] = fmaf(ak, Wl[k * C + c], o[c]);
    }

    float mx = o[0];
#pragma unroll
    for (int c = 1; c < C; ++c) mx = fmaxf(mx, o[c]);
    unsigned long long m = __ballot(mx > 0.f);
    if (m != 0ull && (threadIdx.x & 63) == (__ffsll((long long)m) - 1))
        atomicOr(needflag, 1);

    float4* orow = reinterpret_cast<float4*>(y + (size_t)i * C);
#pragma unroll
    for (int q = 0; q < CV; ++q) {
        float4 v = {o[q * 4 + 0], o[q * 4 + 1], o[q * 4 + 2], o[q * 4 + 3]};
        orow[q] = v;
    }
}

// ---- binpass: bin edges into 782 coarse buckets (gated, chunk loop) ---------
__global__ void binpass_kernel(const int* __restrict__ ei,
                               int* __restrict__ gcur,
                               int* __restrict__ bucketed,
                               const int* __restrict__ gate) {
    if (*gate == 0) return;
    __shared__ int hist[NB];
    __shared__ int base[NB];
    int tid = threadIdx.x;

    for (int chunk = blockIdx.x; chunk < NBLK_BIN; chunk += gridDim.x) {
        for (int b = tid; b < NB; b += 256) hist[b] = 0;
        __syncthreads();

        int e0 = chunk * BE;
        int e1 = min(e0 + BE, N_EDGES);
        for (int e = e0 + tid; e < e1; e += 256)
            atomicAdd(&hist[ei[N_EDGES + e] >> 7], 1);
        __syncthreads();

        for (int b = tid; b < NB; b += 256) {
            int c = hist[b];
            base[b] = c ? atomicAdd(&gcur[b], c) : 0;
            hist[b] = 0;                  // reuse as local cursor
        }
        __syncthreads();

        for (int e = e0 + tid; e < e1; e += 256) {
            int s = ei[e];
            int d = ei[N_EDGES + e];
            int b = d >> 7;
            int lp = atomicAdd(&hist[b], 1);
            int pos = base[b] + lp;
            if (pos < BCAP) bucketed[b * BCAP + pos] = (s << 7) | (d & 127);
        }
        __syncthreads();                  // safe LDS reuse next chunk
    }
}

// ---- localsort: per-bucket counting sort on key (dst, src_tile) -------------
// Inlines the 782-bucket exclusive scan (redundant per block, ~3 KB LDS read).
__global__ void localsort_kernel(const int* __restrict__ gcur,
                                 const int* __restrict__ bucketed,
                                 int* __restrict__ offsets,
                                 int* __restrict__ sorted_src,
                                 const int* __restrict__ gate) {
    if (*gate == 0) return;
    __shared__ int bb[NB];                // exclusive scan of bucket counts
    __shared__ int cnt[128 * NT];
    __shared__ int loff[128 * NT];
    __shared__ int pbuf[2][256];
    int tid = threadIdx.x;

    // ---- block-local scan of gcur[0..NB) into bb ----
    {
        int v[4];
        int sum = 0;
#pragma unroll
        for (int k = 0; k < 4; ++k) {
            int idx = tid * 4 + k;
            v[k] = (idx < NB) ? gcur[idx] : 0;
            sum += v[k];
        }
        pbuf[0][tid] = sum;
        __syncthreads();
        int p = 0;
        for (int d = 1; d < 256; d <<= 1) {
            int t = pbuf[p][tid];
            if (tid >= d) t += pbuf[p][tid - d];
            pbuf[p ^ 1][tid] = t;
            __syncthreads();
            p ^= 1;
        }
        int excl = pbuf[p][tid] - sum;
#pragma unroll
        for (int k = 0; k < 4; ++k) {
            int idx = tid * 4 + k;
            if (idx < NB) bb[idx] = excl;
            excl += v[k];
        }
        __syncthreads();
    }

    for (int b = blockIdx.x; b < NB; b += gridDim.x) {
        int c = min(gcur[b], BCAP);
        int base = bb[b];

        for (int k = tid; k < 128 * NT; k += 256) cnt[k] = 0;
        __syncthreads();

        for (int j = tid; j < c; j += 256) {
            int v = bucketed[b * BCAP + j];
            int key = ((v & 127) << 4) | ((v >> 7) >> 13);
            atomicAdd(&cnt[key], 1);
        }
        __syncthreads();

        // 2-level exclusive scan over 2048 counters: 8 keys per thread
        int sum = 0;
#pragma unroll
        for (int k = 0; k < 8; ++k) sum += cnt[tid * 8 + k];
        pbuf[0][tid] = sum;
        __syncthreads();
        int p = 0;
        for (int d = 1; d < 256; d <<= 1) {
            int t = pbuf[p][tid];
            if (tid >= d) t += pbuf[p][tid - d];
            pbuf[p ^ 1][tid] = t;
            __syncthreads();
            p ^= 1;
        }
        int run = pbuf[p][tid] - sum;
#pragma unroll
        for (int k = 0; k < 8; ++k) { loff[tid * 8 + k] = run; run += cnt[tid * 8 + k]; }
        __syncthreads();

        int gd = b * 128 + tid;
        if (tid < 128 && gd < N_NODES) offsets[gd] = base + loff[tid << 4];
        if (b == NB - 1 && tid == 0) offsets[N_NODES] = N_EDGES;

        for (int k = tid; k < 128 * NT; k += 256) cnt[k] = 0;  // reuse as cursors
        __syncthreads();

        for (int j = tid; j < c; j += 256) {
            int v = bucketed[b * BCAP + j];
            int s = v >> 7;
            int key = ((v & 127) << 4) | (s >> 13);
            int lp = atomicAdd(&cnt[key], 1);
            sorted_src[base + loff[key] + lp] = s;
        }
        __syncthreads();                  // safe LDS reuse next bucket
    }
}

// ---- gather: pull-mode sum, 4-deep pipelined, grid-stride (gated) -----------
__global__ void gather_kernel(const float* __restrict__ y,
                              const int* __restrict__ offsets,
                              const int* __restrict__ sorted_src,
                              float* __restrict__ agg,
                              const int* __restrict__ skipflag,
                              int* __restrict__ outflag) {
    if (*skipflag == 0) return;

    const int stride = gridDim.x * blockDim.x;
    for (int t = blockIdx.x * blockDim.x + threadIdx.x;
         t < N_NODES * CV; t += stride) {
        int i = t / CV;
        int q = t - i * CV;
        int beg = offsets[i], end = offsets[i + 1];
        const float* base = y + (size_t)q * 4;

        float4 a0 = {0.f,0.f,0.f,0.f}, a1 = {0.f,0.f,0.f,0.f};
        float4 a2 = {0.f,0.f,0.f,0.f}, a3 = {0.f,0.f,0.f,0.f};

        int j = beg;
        for (; j + 4 <= end; j += 4) {
            int s0 = sorted_src[j + 0];
            int s1 = sorted_src[j + 1];
            int s2 = sorted_src[j + 2];
            int s3 = sorted_src[j + 3];
            float4 v0 = *reinterpret_cast<const float4*>(base + (size_t)s0 * C);
            float4 v1 = *reinterpret_cast<const float4*>(base + (size_t)s1 * C);
            float4 v2 = *reinterpret_cast<const float4*>(base + (size_t)s2 * C);
            float4 v3 = *reinterpret_cast<const float4*>(base + (size_t)s3 * C);
            a0.x += v0.x; a0.y += v0.y; a0.z += v0.z; a0.w += v0.w;
            a1.x += v1.x; a1.y += v1.y; a1.z += v1.z; a1.w += v1.w;
            a2.x += v2.x; a2.y += v2.y; a2.z += v2.z; a2.w += v2.w;
            a3.x += v3.x; a3.y += v3.y; a3.z += v3.z; a3.w += v3.w;
        }
        for (; j < end; ++j) {
            int s = sorted_src[j];
            float4 v = *reinterpret_cast<const float4*>(base + (size_t)s * C);
            a0.x += v.x; a0.y += v.y; a0.z += v.z; a0.w += v.w;
        }

        float4 acc;
        acc.x = (a0.x + a1.x) + (a2.x + a3.x);
        acc.y = (a0.y + a1.y) + (a2.y + a3.y);
        acc.z = (a0.z + a1.z) + (a2.z + a3.z);
        acc.w = (a0.w + a1.w) + (a2.w + a3.w);
        *reinterpret_cast<float4*>(agg + (size_t)i * C + q * 4) = acc;

        if (outflag) {
            bool pos = (acc.x > 0.f) | (acc.y > 0.f) | (acc.z > 0.f) | (acc.w > 0.f);
            unsigned long long m = __ballot(pos);
            if (m != 0ull && (threadIdx.x & 63) == (__ffsll((long long)m) - 1))
                atomicOr(outflag, 1);
        }
    }
}

// ---- prep1: y1 = (relu(agg)/||relu(agg)||) @ W1; gated by posflag -----------
__global__ void prep1_kernel(const float* __restrict__ agg,
                             const float* __restrict__ W,
                             float* __restrict__ y,
                             const int* __restrict__ skipflag) {
    if (*skipflag == 0) return;

    __shared__ float Wl[C * C];
    for (int k = threadIdx.x; k < C * C; k += blockDim.x) Wl[k] = W[k];
    __syncthreads();

    int i = blockIdx.x * blockDim.x + threadIdx.x;
    if (i >= N_NODES) return;

    float a[C];
    const float4* row = reinterpret_cast<const float4*>(agg + (size_t)i * C);
    float ss = 0.f;
#pragma unroll
    for (int q = 0; q < CV; ++q) {
        float4 v = row[q];
        float p0 = fmaxf(v.x, 0.f), p1 = fmaxf(v.y, 0.f);
        float p2 = fmaxf(v.z, 0.f), p3 = fmaxf(v.w, 0.f);
        a[q * 4 + 0] = p0; a[q * 4 + 1] = p1; a[q * 4 + 2] = p2; a[q * 4 + 3] = p3;
        ss += p0 * p0 + p1 * p1 + p2 * p2 + p3 * p3;
    }
    float inv = 1.0f / (sqrtf(ss) + 1e-15f);
#pragma unroll
    for (int c = 0; c < C; ++c) a[c] *= inv;

    float o[C];
#pragma unroll
    for (int c = 0; c < C; ++c) o[c] = 0.f;
    for (int k = 0; k < C; ++k) {
        float ak = a[k];
#pragma unroll
        for (int c = 0; c < C; ++c) o[c] = fmaf(ak, Wl[k * C + c], o[c]);
    }

    float4* orow = reinterpret_cast<float4*>(y + (size_t)i * C);
#pragma unroll
    for (int q = 0; q < CV; ++q) {
        float4 v = {o[q * 4 + 0], o[q * 4 + 1], o[q * 4 + 2], o[q * 4 + 3]};
        orow[q] = v;
    }
}

// ---- final: out[i] = softmax(relu(agg[i])); flag==0 -> softmax(zeros) -------
__global__ void final_kernel(const float* __restrict__ agg,
                             float* __restrict__ out,
                             const int* __restrict__ flag) {
    int i = blockIdx.x * blockDim.x + threadIdx.x;
    if (i >= N_NODES) return;

    float o[C];
    if (*flag != 0) {
        const float4* row = reinterpret_cast<const float4*>(agg + (size_t)i * C);
#pragma unroll
        for (int q = 0; q < CV; ++q) {
            float4 v = row[q];
            o[q * 4 + 0] = fmaxf(v.x, 0.f); o[q * 4 + 1] = fmaxf(v.y, 0.f);
            o[q * 4 + 2] = fmaxf(v.z, 0.f); o[q * 4 + 3] = fmaxf(v.w, 0.f);
        }
    } else {
#pragma unroll
        for (int c = 0; c < C; ++c) o[c] = 0.f;   // bit-identical to reading zeros
    }
    float m = o[0];
#pragma unroll
    for (int c = 1; c < C; ++c) m = fmaxf(m, o[c]);
    float s = 0.f;
#pragma unroll
    for (int c = 0; c < C; ++c) { o[c] = expf(o[c] - m); s += o[c]; }
    float inv = 1.0f / s;

    float4* orow = reinterpret_cast<float4*>(out + (size_t)i * C);
#pragma unroll
    for (int q = 0; q < CV; ++q) {
        float4 v = {o[q * 4 + 0] * inv, o[q * 4 + 1] * inv,
                    o[q * 4 + 2] * inv, o[q * 4 + 3] * inv};
        orow[q] = v;
    }
}

extern "C" void kernel_launch(void* const* d_in, const int* in_sizes, int n_in,
                              void* d_out, int out_size, void* d_ws, size_t ws_size,
                              hipStream_t stream) {
    const float* x  = (const float*)d_in[0];
    const float* Ws = (const float*)d_in[1];   // [2, 40, 40]
    const int*   ei = (const int*)d_in[2];     // [2, 2M]

    // d_out doubles as the row-major y table (16 MB); final overwrites it
    // reading only from ws, so no aliasing race.
    float* y   = (float*)d_out;
    float* out = (float*)d_out;

    // workspace layout (ints), total ~24.4 MB
    int* wsI        = (int*)d_ws;
    int* gcur       = wsI;                     // [0, 1024)
    int* flags      = wsI + 2040;              // [0]=posflag, [1]=needflag
    int* posflag    = flags;
    int* needflag   = flags + 1;
    int* offsets    = wsI + 2048;              // N_NODES+1 (reserve 102400)
    int* sorted_src = wsI + 104448;            // 2,000,000
    int* bucketed   = wsI + 2104448;           // NB*BCAP ints, aliases agg
    float* agg      = (float*)(wsI + 2104448); // 4,000,000 floats

    const int BT = 256;

    // ---- init (replaces 2 memsets) ----
    init_kernel<<<1, BT, 0, stream>>>(gcur, flags);

    // ---- prep0: y0 + branch-and-bound gate ----
    prep0_kernel<<<NODE_BLK, BT, 0, stream>>>(x, Ws, y, needflag);

    // ---- CSR build (gated on needflag; kernel-boundary acquire makes gate safe)
    binpass_kernel<<<256, BT, 0, stream>>>(ei, gcur, bucketed, needflag);
    localsort_kernel<<<391, BT, 0, stream>>>(gcur, bucketed, offsets,
                                             sorted_src, needflag);

    // ---- iteration 0 aggregation (gated; sets posflag) ----
    gather_kernel<<<1024, BT, 0, stream>>>(y, offsets, sorted_src, agg,
                                           needflag, posflag);

    // ---- iteration 1 (gated by posflag) ----
    prep1_kernel<<<NODE_BLK, BT, 0, stream>>>(agg, Ws + C * C, y, posflag);
    gather_kernel<<<1024, BT, 0, stream>>>(y, offsets, sorted_src, agg,
                                           posflag, nullptr);

    // ---- final relu+softmax ----
    final_kernel<<<NODE_BLK, BT, 0, stream>>>(agg, out, posflag);
}

// Round 11
// 37.104 us; speedup vs baseline: 5.6457x; 1.1350x over previous
//
#include <hip/hip_runtime.h>
#include <math.h>

// GeneralLPModel: 2 x { row-normalize -> scatter-add(edges) -> relu(agg @ W) } -> softmax
// R11: R10 structure, dispatches 8 -> 7.
//  - init_kernel removed: prep0 zeroes gcur+posflag (block 0); needflag pre-zero
//    eliminated via per-block unconditional verdict array needarr[NODE_BLK].
//  - binpass gates on a scan of needarr; its block 0 reduces needarr -> needflag
//    for the cheaper single-word gates downstream (kernel-boundary visibility).
//  - gather grid 1024 -> 512 (grid-stride), halving empty-dispatch drain.
// All cross-kernel flag communication stays at kernel granularity (acquire
// semantics at dispatch boundaries -- the R9 lesson).

constexpr int N_NODES = 100000;
constexpr int N_EDGES = 2000000;
constexpr int C       = 40;
constexpr int CV      = C / 4;        // 10 float4 chunks per row
constexpr int NB      = 782;          // coarse buckets: dst>>7
constexpr int BCAP    = 3072;         // per-bucket capacity (mean 2560, +10 sigma)
constexpr int BE      = 4096;         // edges per binpass chunk
constexpr int NBLK_BIN = (N_EDGES + BE - 1) / BE;   // 489 chunks
constexpr int NODE_BLK = (N_NODES + 255) / 256;     // 391
constexpr int NT      = 16;           // src tiles (src>>13)

// ---- prep0: y0 = (x/(||x||+eps)) @ W0; needarr[b] = block-any(y0>0);
//      block 0 also zeroes gcur + posflag (consumed only after this kernel). --
__global__ void prep0_kernel(const float* __restrict__ x,
                             const float* __restrict__ W,
                             float* __restrict__ y,
                             int* __restrict__ needarr,
                             int* __restrict__ gcur,
                             int* __restrict__ posflag) {
    __shared__ float Wl[C * C];
    __shared__ int sneed;
    if (threadIdx.x == 0) sneed = 0;
    for (int k = threadIdx.x; k < C * C; k += blockDim.x) Wl[k] = W[k];
    __syncthreads();

    if (blockIdx.x == 0) {
        for (int k = threadIdx.x; k < NB; k += blockDim.x) gcur[k] = 0;
        if (threadIdx.x == 0) *posflag = 0;
    }

    int i = blockIdx.x * blockDim.x + threadIdx.x;
    bool mypos = false;
    if (i < N_NODES) {
        float a[C];
        const float4* row = reinterpret_cast<const float4*>(x + (size_t)i * C);
        float ss = 0.f;
#pragma unroll
        for (int q = 0; q < CV; ++q) {
            float4 v = row[q];
            a[q * 4 + 0] = v.x; a[q * 4 + 1] = v.y;
            a[q * 4 + 2] = v.z; a[q * 4 + 3] = v.w;
            ss += v.x * v.x + v.y * v.y + v.z * v.z + v.w * v.w;
        }
        float inv = 1.0f / (sqrtf(ss) + 1e-15f);
#pragma unroll
        for (int c = 0; c < C; ++c) a[c] *= inv;

        float o[C];
#pragma unroll
        for (int c = 0; c < C; ++c) o[c] = 0.f;
        for (int k = 0; k < C; ++k) {
            float ak = a[k];
#pragma unroll
            for (int c = 0; c < C; ++c) o[c] = fmaf(ak, Wl[k * C + c], o[c]);
        }

        float mx = o[0];
#pragma unroll
        for (int c = 1; c < C; ++c) mx = fmaxf(mx, o[c]);
        mypos = (mx > 0.f);

        float4* orow = reinterpret_cast<float4*>(y + (size_t)i * C);
#pragma unroll
        for (int q = 0; q < CV; ++q) {
            float4 v = {o[q * 4 + 0], o[q * 4 + 1], o[q * 4 + 2], o[q * 4 + 3]};
            orow[q] = v;
        }
    }
    if (mypos) sneed = 1;                 // benign race: all writers store 1
    __syncthreads();
    if (threadIdx.x == 0) needarr[blockIdx.x] = sneed;   // unconditional write
}

// ---- block-uniform gate from needarr ----------------------------------------
__device__ __forceinline__ bool needarr_gate(const int* __restrict__ needarr,
                                             int* sgate) {
    if (threadIdx.x == 0) *sgate = 0;
    __syncthreads();
    int v = 0;
    for (int k = threadIdx.x; k < NODE_BLK; k += 256) v |= needarr[k];
    if (v) *sgate = 1;                    // benign race
    __syncthreads();
    return *sgate != 0;
}

// ---- binpass: bin edges into 782 coarse buckets (gated on needarr) ----------
// Block 0 additionally reduces needarr -> needflag for downstream kernels.
__global__ void binpass_kernel(const int* __restrict__ ei,
                               int* __restrict__ gcur,
                               int* __restrict__ bucketed,
                               const int* __restrict__ needarr,
                               int* __restrict__ needflag) {
    __shared__ int sgate;
    __shared__ int hist[NB];
    __shared__ int base[NB];
    bool need = needarr_gate(needarr, &sgate);
    if (blockIdx.x == 0 && threadIdx.x == 0) *needflag = need ? 1 : 0;
    if (!need) return;

    int tid = threadIdx.x;
    for (int chunk = blockIdx.x; chunk < NBLK_BIN; chunk += gridDim.x) {
        for (int b = tid; b < NB; b += 256) hist[b] = 0;
        __syncthreads();

        int e0 = chunk * BE;
        int e1 = min(e0 + BE, N_EDGES);
        for (int e = e0 + tid; e < e1; e += 256)
            atomicAdd(&hist[ei[N_EDGES + e] >> 7], 1);
        __syncthreads();

        for (int b = tid; b < NB; b += 256) {
            int c = hist[b];
            base[b] = c ? atomicAdd(&gcur[b], c) : 0;
            hist[b] = 0;                  // reuse as local cursor
        }
        __syncthreads();

        for (int e = e0 + tid; e < e1; e += 256) {
            int s = ei[e];
            int d = ei[N_EDGES + e];
            int b = d >> 7;
            int lp = atomicAdd(&hist[b], 1);
            int pos = base[b] + lp;
            if (pos < BCAP) bucketed[b * BCAP + pos] = (s << 7) | (d & 127);
        }
        __syncthreads();                  // safe LDS reuse next chunk
    }
}

// ---- localsort: per-bucket counting sort on key (dst, src_tile) -------------
// Inlines the 782-bucket exclusive scan (redundant per block).
__global__ void localsort_kernel(const int* __restrict__ gcur,
                                 const int* __restrict__ bucketed,
                                 int* __restrict__ offsets,
                                 int* __restrict__ sorted_src,
                                 const int* __restrict__ gate) {
    if (*gate == 0) return;
    __shared__ int bb[NB];                // exclusive scan of bucket counts
    __shared__ int cnt[128 * NT];
    __shared__ int loff[128 * NT];
    __shared__ int pbuf[2][256];
    int tid = threadIdx.x;

    // ---- block-local scan of gcur[0..NB) into bb ----
    {
        int v[4];
        int sum = 0;
#pragma unroll
        for (int k = 0; k < 4; ++k) {
            int idx = tid * 4 + k;
            v[k] = (idx < NB) ? gcur[idx] : 0;
            sum += v[k];
        }
        pbuf[0][tid] = sum;
        __syncthreads();
        int p = 0;
        for (int d = 1; d < 256; d <<= 1) {
            int t = pbuf[p][tid];
            if (tid >= d) t += pbuf[p][tid - d];
            pbuf[p ^ 1][tid] = t;
            __syncthreads();
            p ^= 1;
        }
        int excl = pbuf[p][tid] - sum;
#pragma unroll
        for (int k = 0; k < 4; ++k) {
            int idx = tid * 4 + k;
            if (idx < NB) bb[idx] = excl;
            excl += v[k];
        }
        __syncthreads();
    }

    for (int b = blockIdx.x; b < NB; b += gridDim.x) {
        int c = min(gcur[b], BCAP);
        int base = bb[b];

        for (int k = tid; k < 128 * NT; k += 256) cnt[k] = 0;
        __syncthreads();

        for (int j = tid; j < c; j += 256) {
            int v = bucketed[b * BCAP + j];
            int key = ((v & 127) << 4) | ((v >> 7) >> 13);
            atomicAdd(&cnt[key], 1);
        }
        __syncthreads();

        // 2-level exclusive scan over 2048 counters: 8 keys per thread
        int sum = 0;
#pragma unroll
        for (int k = 0; k < 8; ++k) sum += cnt[tid * 8 + k];
        pbuf[0][tid] = sum;
        __syncthreads();
        int p = 0;
        for (int d = 1; d < 256; d <<= 1) {
            int t = pbuf[p][tid];
            if (tid >= d) t += pbuf[p][tid - d];
            pbuf[p ^ 1][tid] = t;
            __syncthreads();
            p ^= 1;
        }
        int run = pbuf[p][tid] - sum;
#pragma unroll
        for (int k = 0; k < 8; ++k) { loff[tid * 8 + k] = run; run += cnt[tid * 8 + k]; }
        __syncthreads();

        int gd = b * 128 + tid;
        if (tid < 128 && gd < N_NODES) offsets[gd] = base + loff[tid << 4];
        if (b == NB - 1 && tid == 0) offsets[N_NODES] = N_EDGES;

        for (int k = tid; k < 128 * NT; k += 256) cnt[k] = 0;  // reuse as cursors
        __syncthreads();

        for (int j = tid; j < c; j += 256) {
            int v = bucketed[b * BCAP + j];
            int s = v >> 7;
            int key = ((v & 127) << 4) | (s >> 13);
            int lp = atomicAdd(&cnt[key], 1);
            sorted_src[base + loff[key] + lp] = s;
        }
        __syncthreads();                  // safe LDS reuse next bucket
    }
}

// ---- gather: pull-mode sum, 4-deep pipelined, grid-stride (gated) -----------
__global__ void gather_kernel(const float* __restrict__ y,
                              const int* __restrict__ offsets,
                              const int* __restrict__ sorted_src,
                              float* __restrict__ agg,
                              const int* __restrict__ skipflag,
                              int* __restrict__ outflag) {
    if (*skipflag == 0) return;

    const int stride = gridDim.x * blockDim.x;
    for (int t = blockIdx.x * blockDim.x + threadIdx.x;
         t < N_NODES * CV; t += stride) {
        int i = t / CV;
        int q = t - i * CV;
        int beg = offsets[i], end = offsets[i + 1];
        const float* base = y + (size_t)q * 4;

        float4 a0 = {0.f,0.f,0.f,0.f}, a1 = {0.f,0.f,0.f,0.f};
        float4 a2 = {0.f,0.f,0.f,0.f}, a3 = {0.f,0.f,0.f,0.f};

        int j = beg;
        for (; j + 4 <= end; j += 4) {
            int s0 = sorted_src[j + 0];
            int s1 = sorted_src[j + 1];
            int s2 = sorted_src[j + 2];
            int s3 = sorted_src[j + 3];
            float4 v0 = *reinterpret_cast<const float4*>(base + (size_t)s0 * C);
            float4 v1 = *reinterpret_cast<const float4*>(base + (size_t)s1 * C);
            float4 v2 = *reinterpret_cast<const float4*>(base + (size_t)s2 * C);
            float4 v3 = *reinterpret_cast<const float4*>(base + (size_t)s3 * C);
            a0.x += v0.x; a0.y += v0.y; a0.z += v0.z; a0.w += v0.w;
            a1.x += v1.x; a1.y += v1.y; a1.z += v1.z; a1.w += v1.w;
            a2.x += v2.x; a2.y += v2.y; a2.z += v2.z; a2.w += v2.w;
            a3.x += v3.x; a3.y += v3.y; a3.z += v3.z; a3.w += v3.w;
        }
        for (; j < end; ++j) {
            int s = sorted_src[j];
            float4 v = *reinterpret_cast<const float4*>(base + (size_t)s * C);
            a0.x += v.x; a0.y += v.y; a0.z += v.z; a0.w += v.w;
        }

        float4 acc;
        acc.x = (a0.x + a1.x) + (a2.x + a3.x);
        acc.y = (a0.y + a1.y) + (a2.y + a3.y);
        acc.z = (a0.z + a1.z) + (a2.z + a3.z);
        acc.w = (a0.w + a1.w) + (a2.w + a3.w);
        *reinterpret_cast<float4*>(agg + (size_t)i * C + q * 4) = acc;

        if (outflag) {
            bool pos = (acc.x > 0.f) | (acc.y > 0.f) | (acc.z > 0.f) | (acc.w > 0.f);
            unsigned long long m = __ballot(pos);
            if (m != 0ull && (threadIdx.x & 63) == (__ffsll((long long)m) - 1))
                atomicOr(outflag, 1);
        }
    }
}

// ---- prep1: y1 = (relu(agg)/||relu(agg)||) @ W1; gated by posflag -----------
__global__ void prep1_kernel(const float* __restrict__ agg,
                             const float* __restrict__ W,
                             float* __restrict__ y,
                             const int* __restrict__ skipflag) {
    if (*skipflag == 0) return;

    __shared__ float Wl[C * C];
    for (int k = threadIdx.x; k < C * C; k += blockDim.x) Wl[k] = W[k];
    __syncthreads();

    int i = blockIdx.x * blockDim.x + threadIdx.x;
    if (i >= N_NODES) return;

    float a[C];
    const float4* row = reinterpret_cast<const float4*>(agg + (size_t)i * C);
    float ss = 0.f;
#pragma unroll
    for (int q = 0; q < CV; ++q) {
        float4 v = row[q];
        float p0 = fmaxf(v.x, 0.f), p1 = fmaxf(v.y, 0.f);
        float p2 = fmaxf(v.z, 0.f), p3 = fmaxf(v.w, 0.f);
        a[q * 4 + 0] = p0; a[q * 4 + 1] = p1; a[q * 4 + 2] = p2; a[q * 4 + 3] = p3;
        ss += p0 * p0 + p1 * p1 + p2 * p2 + p3 * p3;
    }
    float inv = 1.0f / (sqrtf(ss) + 1e-15f);
#pragma unroll
    for (int c = 0; c < C; ++c) a[c] *= inv;

    float o[C];
#pragma unroll
    for (int c = 0; c < C; ++c) o[c] = 0.f;
    for (int k = 0; k < C; ++k) {
        float ak = a[k];
#pragma unroll
        for (int c = 0; c < C; ++c) o[c] = fmaf(ak, Wl[k * C + c], o[c]);
    }

    float4* orow = reinterpret_cast<float4*>(y + (size_t)i * C);
#pragma unroll
    for (int q = 0; q < CV; ++q) {
        float4 v = {o[q * 4 + 0], o[q * 4 + 1], o[q * 4 + 2], o[q * 4 + 3]};
        orow[q] = v;
    }
}

// ---- final: out[i] = softmax(relu(agg[i])); flag==0 -> softmax(zeros) -------
__global__ void final_kernel(const float* __restrict__ agg,
                             float* __restrict__ out,
                             const int* __restrict__ flag) {
    int i = blockIdx.x * blockDim.x + threadIdx.x;
    if (i >= N_NODES) return;

    float o[C];
    if (*flag != 0) {
        const float4* row = reinterpret_cast<const float4*>(agg + (size_t)i * C);
#pragma unroll
        for (int q = 0; q < CV; ++q) {
            float4 v = row[q];
            o[q * 4 + 0] = fmaxf(v.x, 0.f); o[q * 4 + 1] = fmaxf(v.y, 0.f);
            o[q * 4 + 2] = fmaxf(v.z, 0.f); o[q * 4 + 3] = fmaxf(v.w, 0.f);
        }
    } else {
#pragma unroll
        for (int c = 0; c < C; ++c) o[c] = 0.f;   // bit-identical to reading zeros
    }
    float m = o[0];
#pragma unroll
    for (int c = 1; c < C; ++c) m = fmaxf(m, o[c]);
    float s = 0.f;
#pragma unroll
    for (int c = 0; c < C; ++c) { o[c] = expf(o[c] - m); s += o[c]; }
    float inv = 1.0f / s;

    float4* orow = reinterpret_cast<float4*>(out + (size_t)i * C);
#pragma unroll
    for (int q = 0; q < CV; ++q) {
        float4 v = {o[q * 4 + 0] * inv, o[q * 4 + 1] * inv,
                    o[q * 4 + 2] * inv, o[q * 4 + 3] * inv};
        orow[q] = v;
    }
}

extern "C" void kernel_launch(void* const* d_in, const int* in_sizes, int n_in,
                              void* d_out, int out_size, void* d_ws, size_t ws_size,
                              hipStream_t stream) {
    const float* x  = (const float*)d_in[0];
    const float* Ws = (const float*)d_in[1];   // [2, 40, 40]
    const int*   ei = (const int*)d_in[2];     // [2, 2M]

    // d_out doubles as the row-major y table (16 MB); final overwrites it
    // reading only from ws, so no aliasing race.
    float* y   = (float*)d_out;
    float* out = (float*)d_out;

    // workspace layout (ints), total ~24.4 MB
    int* wsI        = (int*)d_ws;
    int* gcur       = wsI;                     // [0, 1024)
    int* needarr    = wsI + 1024;              // [1024, 1415): per-block verdicts
    int* posflag    = wsI + 2040;
    int* needflag   = wsI + 2041;
    int* offsets    = wsI + 2048;              // N_NODES+1 (reserve 102400)
    int* sorted_src = wsI + 104448;            // 2,000,000
    int* bucketed   = wsI + 2104448;           // NB*BCAP ints, aliases agg
    float* agg      = (float*)(wsI + 2104448); // 4,000,000 floats

    const int BT = 256;

    // ---- prep0: y0 + per-block need verdicts; zeroes gcur + posflag ----
    prep0_kernel<<<NODE_BLK, BT, 0, stream>>>(x, Ws, y, needarr, gcur, posflag);

    // ---- CSR build (gated; binpass reduces needarr -> needflag) ----
    binpass_kernel<<<256, BT, 0, stream>>>(ei, gcur, bucketed, needarr, needflag);
    localsort_kernel<<<391, BT, 0, stream>>>(gcur, bucketed, offsets,
                                             sorted_src, needflag);

    // ---- iteration 0 aggregation (gated; sets posflag) ----
    gather_kernel<<<512, BT, 0, stream>>>(y, offsets, sorted_src, agg,
                                          needflag, posflag);

    // ---- iteration 1 (gated by posflag) ----
    prep1_kernel<<<NODE_BLK, BT, 0, stream>>>(agg, Ws + C * C, y, posflag);
    gather_kernel<<<512, BT, 0, stream>>>(y, offsets, sorted_src, agg,
                                          posflag, nullptr);

    // ---- final relu+softmax ----
    final_kernel<<<NODE_BLK, BT, 0, stream>>>(agg, out, posflag);
}